// Round 2
// baseline (2022.588 us; speedup 1.0000x reference)
//
#include <hip/hip_runtime.h>
#include <hip/hip_bf16.h>

#define TTOK 8192
#define HDIM 1024
#define ENUM 8
#define CAP  1280
#define IRD  4096
#define ISH  8192

typedef __hip_bfloat16 bf16;
typedef __bf16 bf16x8 __attribute__((ext_vector_type(8)));
typedef float f32x4 __attribute__((ext_vector_type(4)));

#define AS1(p) ((const __attribute__((address_space(1))) void*)(p))
#define AS3(p) ((__attribute__((address_space(3))) void*)(p))

// ---------------- router: RMSNorm (f32) + logits (f32) + top-2 ----------------
__global__ __launch_bounds__(256) void router_kernel(
    const float* __restrict__ x, const float* __restrict__ rtw,
    bf16* __restrict__ xb,
    int* __restrict__ e0a, int* __restrict__ e1a,
    float* __restrict__ w0a, float* __restrict__ w1a)
{
    __shared__ float row[HDIM];
    __shared__ float ssred[4];
    __shared__ float lgl[ENUM];
    const int t = blockIdx.x;
    const int tid = threadIdx.x;
    const int lane = tid & 63, wv = tid >> 6;
    const float* xr = x + (size_t)t * HDIM;
    bf16* xbr = xb + (size_t)t * HDIM;
    float ss = 0.f;
    for (int i = tid; i < HDIM; i += 256) {
        float v = xr[i];
        row[i] = v;
        ss += v * v;
        xbr[i] = __float2bfloat16(v);
    }
    #pragma unroll
    for (int o = 32; o > 0; o >>= 1) ss += __shfl_down(ss, o, 64);
    if (lane == 0) ssred[wv] = ss;
    __syncthreads();
    for (int ee = 0; ee < 2; ++ee) {
        const int e = wv * 2 + ee;
        const float* we = rtw + e * HDIM;
        float p = 0.f;
        for (int i = lane; i < HDIM; i += 64) p += row[i] * we[i];
        #pragma unroll
        for (int o = 32; o > 0; o >>= 1) p += __shfl_down(p, o, 64);
        if (lane == 0) lgl[e] = p;
    }
    __syncthreads();
    if (tid == 0) {
        float tot = ssred[0] + ssred[1] + ssred[2] + ssred[3];
        float rstd = rsqrtf(tot / (float)HDIM + 1.1920929e-07f);
        float l[ENUM];
        #pragma unroll
        for (int e = 0; e < ENUM; ++e) l[e] = lgl[e] * rstd;
        int b0 = 0;
        #pragma unroll
        for (int e = 1; e < ENUM; ++e) if (l[e] > l[b0]) b0 = e;
        int b1 = (b0 == 0) ? 1 : 0;
        #pragma unroll
        for (int e = 0; e < ENUM; ++e) if (e != b0 && l[e] > l[b1]) b1 = e;
        float w0 = 1.f / (1.f + expf(l[b1] - l[b0]));
        e0a[t] = b0; e1a[t] = b1;
        w0a[t] = w0; w1a[t] = 1.f - w0;
    }
}

// ------------- dispatch: stable compaction per expert + per-slot weight -------
__global__ __launch_bounds__(256) void dispatch_kernel(
    const int* __restrict__ e0a, const int* __restrict__ e1a,
    const float* __restrict__ w0a, const float* __restrict__ w1a,
    int* __restrict__ disp, float* __restrict__ wrow)
{
    const int e = blockIdx.x;
    const int tid = threadIdx.x;
    const int lane = tid & 63, wv = tid >> 6;
    __shared__ int wcnt[4];
    for (int i = tid; i < CAP; i += 256) {
        disp[e * CAP + i] = 0;      // safe filler token
        wrow[e * CAP + i] = 0.f;    // filler weight -> contributes nothing
    }
    __syncthreads();
    int run = 0;
    for (int base = 0; base < TTOK; base += 256) {
        const int t = base + tid;
        const bool f0 = (e0a[t] == e);
        const bool f1 = (e1a[t] == e);
        const bool f = f0 || f1;
        unsigned long long m = __ballot(f);
        int posw = __popcll(m & ((1ULL << lane) - 1ULL));
        if (lane == 0) wcnt[wv] = __popcll(m);
        __syncthreads();
        int off = 0;
        #pragma unroll
        for (int w = 0; w < 4; ++w) if (w < wv) off += wcnt[w];
        const int tot = wcnt[0] + wcnt[1] + wcnt[2] + wcnt[3];
        if (f) {
            const int pos = run + off + posw;
            if (pos < CAP) {
                disp[e * CAP + pos] = t;
                wrow[e * CAP + pos] = f0 ? w0a[t] : w1a[t];
            }
        }
        run += tot;
        __syncthreads();
    }
}

// ----------------------------- gather x rows ---------------------------------
__global__ __launch_bounds__(256) void gather_kernel(
    const int* __restrict__ disp, const bf16* __restrict__ xb, bf16* __restrict__ xg)
{
    const int r = blockIdx.x;
    const int t = disp[r];
    const uint2* s = (const uint2*)(xb + (size_t)t * HDIM);
    uint2* d = (uint2*)(xg + (size_t)r * HDIM);
    d[threadIdx.x] = s[threadIdx.x];
}

// --------------- f32 -> bf16 transpose-convert (weights to [N][K]) -----------
__global__ __launch_bounds__(256) void tcvt_kernel(
    const float* __restrict__ in, bf16* __restrict__ out, int R, int C)
{
    __shared__ float tile[32][33];
    const size_t boff = (size_t)blockIdx.z * R * C;
    const int c0 = blockIdx.x * 32, r0 = blockIdx.y * 32;
    const int tx = threadIdx.x & 31, ty = threadIdx.x >> 5;
    #pragma unroll
    for (int i = 0; i < 4; ++i)
        tile[ty + i * 8][tx] = in[boff + (size_t)(r0 + ty + i * 8) * C + c0 + tx];
    __syncthreads();
    #pragma unroll
    for (int i = 0; i < 4; ++i)
        out[boff + (size_t)(c0 + ty + i * 8) * R + r0 + tx] =
            __float2bfloat16(tile[tx][ty + i * 8]);
}

// ---- fused gate+up GEMM: H = silu(A@Bg^T) * (A@Bu^T), bf16 out --------------
// 128x128 tile, BK=32, dual accumulators, shared A staging + A fragments.
__global__ __launch_bounds__(256, 2) void gemm_gu(
    const bf16* __restrict__ A, const bf16* __restrict__ Bg,
    const bf16* __restrict__ Bu, bf16* __restrict__ H,
    int N, int K, long long sA, long long sB, long long sH)
{
    __shared__ __align__(16) bf16 lds[3 * 4096];   // A | Bg | Bu staging, 24 KB
    bf16* ldsA = lds;
    bf16* ldsG = lds + 4096;
    bf16* ldsU = lds + 8192;
    const int z = blockIdx.z;
    const bf16* Ab  = A  + (long long)z * sA;
    const bf16* Bgb = Bg + (long long)z * sB;
    const bf16* Bub = Bu + (long long)z * sB;
    const int tid = threadIdx.x;
    const int lane = tid & 63, wv = tid >> 6;
    const int m0 = blockIdx.y * 128, n0 = blockIdx.x * 128;
    const int wr = (wv >> 1) * 64, wc = (wv & 1) * 64;
    const int srow = lane >> 2;
    const int skk  = (lane & 3) * 8;
    const int fr = lane & 15, fk = (lane >> 4) * 8;

    f32x4 ag[4][4] = {}, au[4][4] = {};

    for (int k0 = 0; k0 < K; k0 += 32) {
        #pragma unroll
        for (int rr = 0; rr < 2; ++rr) {
            const int c = wv * 2 + rr;
            const int row = c * 16 + srow;
            __builtin_amdgcn_global_load_lds(
                AS1(Ab + (long long)(m0 + row) * K + k0 + skk), AS3(ldsA + c * 512), 16, 0, 0);
            __builtin_amdgcn_global_load_lds(
                AS1(Bgb + (long long)(n0 + row) * K + k0 + skk), AS3(ldsG + c * 512), 16, 0, 0);
            __builtin_amdgcn_global_load_lds(
                AS1(Bub + (long long)(n0 + row) * K + k0 + skk), AS3(ldsU + c * 512), 16, 0, 0);
        }
        __syncthreads();
        bf16x8 af[4], fg[4], fu[4];
        #pragma unroll
        for (int i = 0; i < 4; ++i)
            af[i] = *(const bf16x8*)(ldsA + (wr + i * 16 + fr) * 32 + fk);
        #pragma unroll
        for (int j = 0; j < 4; ++j) {
            fg[j] = *(const bf16x8*)(ldsG + (wc + j * 16 + fr) * 32 + fk);
            fu[j] = *(const bf16x8*)(ldsU + (wc + j * 16 + fr) * 32 + fk);
        }
        #pragma unroll
        for (int i = 0; i < 4; ++i)
            #pragma unroll
            for (int j = 0; j < 4; ++j) {
                ag[i][j] = __builtin_amdgcn_mfma_f32_16x16x32_bf16(af[i], fg[j], ag[i][j], 0, 0, 0);
                au[i][j] = __builtin_amdgcn_mfma_f32_16x16x32_bf16(af[i], fu[j], au[i][j], 0, 0, 0);
            }
        __syncthreads();
    }

    // epilogue: silu(g)*u -> per-wave LDS transpose -> coalesced 16B stores
    bf16* sc = lds + wv * (16 * 72);      // 16 rows x 72-elem padded stride
    const int erow4 = (lane >> 4) * 4;
    #pragma unroll
    for (int i = 0; i < 4; ++i) {
        #pragma unroll
        for (int j = 0; j < 4; ++j)
            #pragma unroll
            for (int r = 0; r < 4; ++r) {
                const float g = ag[i][j][r], u = au[i][j][r];
                const float h = (g / (1.f + __expf(-g))) * u;
                sc[(erow4 + r) * 72 + j * 16 + fr] = __float2bfloat16(h);
            }
        #pragma unroll
        for (int p = 0; p < 2; ++p) {
            const int rl = p * 8 + (lane >> 3);
            const uint4 v = *(const uint4*)(sc + rl * 72 + (lane & 7) * 8);
            *(uint4*)(H + (long long)z * sH +
                      (long long)(m0 + wr + i * 16 + rl) * N + n0 + wc + (lane & 7) * 8) = v;
        }
    }
}

// ---- down GEMM with split-K + atomic epilogue -------------------------------
// MODE 0: shared expert — out[(moff+row)*1024+col] += v    (z = k-split 0..3)
// MODE 1: routed experts — weighted scatter via disp/wrow   (z = e*2 + ksplit)
template <int MODE>
__global__ __launch_bounds__(256, 3) void gemm_down(
    const bf16* __restrict__ A, const bf16* __restrict__ Bw, float* __restrict__ out,
    const int* __restrict__ disp, const float* __restrict__ wrow,
    int Kfull, int moff)
{
    constexpr int N = 1024;
    __shared__ __align__(16) char smem[20480];     // staging 16 KB | epi scratch 20 KB
    bf16* ldsA = (bf16*)smem;
    bf16* ldsB = (bf16*)(smem + 8192);
    const int z = blockIdx.z;
    int kBeg, kLen;
    const bf16* Ab = A; const bf16* Bb = Bw;
    const int* dspE = disp; const float* wrE = wrow;
    if (MODE == 0) {
        kLen = Kfull >> 2; kBeg = z * kLen;
    } else {
        const int e = z >> 1; kLen = Kfull >> 1; kBeg = (z & 1) * kLen;
        Ab += (long long)e * CAP * Kfull;
        Bb += (long long)e * N * Kfull;
        dspE += e * CAP; wrE += e * CAP;
    }
    const int tid = threadIdx.x;
    const int lane = tid & 63, wv = tid >> 6;
    const int m0 = blockIdx.y * 128, n0 = blockIdx.x * 128;
    const int wr = (wv >> 1) * 64, wc = (wv & 1) * 64;
    const int srow = lane >> 2;
    const int skk  = (lane & 3) * 8;
    const int fr = lane & 15, fk = (lane >> 4) * 8;

    f32x4 acc[4][4] = {};

    for (int k0 = kBeg; k0 < kBeg + kLen; k0 += 32) {
        #pragma unroll
        for (int rr = 0; rr < 2; ++rr) {
            const int c = wv * 2 + rr;
            const int row = c * 16 + srow;
            __builtin_amdgcn_global_load_lds(
                AS1(Ab + (long long)(m0 + row) * Kfull + k0 + skk), AS3(ldsA + c * 512), 16, 0, 0);
            __builtin_amdgcn_global_load_lds(
                AS1(Bb + (long long)(n0 + row) * Kfull + k0 + skk), AS3(ldsB + c * 512), 16, 0, 0);
        }
        __syncthreads();
        bf16x8 af[4], bfr[4];
        #pragma unroll
        for (int i = 0; i < 4; ++i)
            af[i] = *(const bf16x8*)(ldsA + (wr + i * 16 + fr) * 32 + fk);
        #pragma unroll
        for (int j = 0; j < 4; ++j)
            bfr[j] = *(const bf16x8*)(ldsB + (wc + j * 16 + fr) * 32 + fk);
        #pragma unroll
        for (int i = 0; i < 4; ++i)
            #pragma unroll
            for (int j = 0; j < 4; ++j)
                acc[i][j] = __builtin_amdgcn_mfma_f32_16x16x32_bf16(af[i], bfr[j], acc[i][j], 0, 0, 0);
        __syncthreads();
    }

    // epilogue: per-wave f32 LDS transpose -> row-major atomic adds
    float* sc = (float*)smem + wv * (16 * 80);     // 16 rows x 80-f32 padded stride
    const int erow4 = (lane >> 4) * 4;
    #pragma unroll
    for (int i = 0; i < 4; ++i) {
        #pragma unroll
        for (int j = 0; j < 4; ++j)
            #pragma unroll
            for (int r = 0; r < 4; ++r)
                sc[(erow4 + r) * 80 + j * 16 + fr] = acc[i][j][r];
        #pragma unroll
        for (int p = 0; p < 4; ++p) {
            const int rl = p * 4 + (lane >> 4);
            const f32x4 v = *(const f32x4*)(sc + rl * 80 + (lane & 15) * 4);
            const int grow = m0 + wr + i * 16 + rl;
            const int col = n0 + wc + (lane & 15) * 4;
            if (MODE == 0) {
                float* o = out + (long long)(moff + grow) * N + col;
                #pragma unroll
                for (int q = 0; q < 4; ++q) atomicAdd(o + q, v[q]);
            } else {
                const float w = wrE[grow];
                if (w != 0.f) {
                    const int t = dspE[grow];
                    float* o = out + (long long)t * N + col;
                    #pragma unroll
                    for (int q = 0; q < 4; ++q) atomicAdd(o + q, w * v[q]);
                }
            }
        }
    }
}

extern "C" void kernel_launch(void* const* d_in, const int* in_sizes, int n_in,
                              void* d_out, int out_size, void* d_ws, size_t ws_size,
                              hipStream_t stream)
{
    const float* x   = (const float*)d_in[0];
    const float* rtw = (const float*)d_in[1];
    const float* rg  = (const float*)d_in[2];
    const float* ru  = (const float*)d_in[3];
    const float* rd  = (const float*)d_in[4];
    const float* sg  = (const float*)d_in[5];
    const float* su  = (const float*)d_in[6];
    const float* sd  = (const float*)d_in[7];
    float* out = (float*)d_out;

    // workspace layout (~256 MB)
    char* w = (char*)d_ws;
    auto alloc = [&](size_t n) { char* p = w; w += (n + 255) & ~(size_t)255; return p; };
    bf16*  xb   = (bf16*)alloc((size_t)TTOK * HDIM * 2);            // 16.8 MB
    bf16*  xg   = (bf16*)alloc((size_t)ENUM * CAP * HDIM * 2);      // 21.0 MB
    bf16*  hbuf = (bf16*)alloc((size_t)ENUM * CAP * IRD * 2);       // 83.9 MB (routed h / shared h chunk)
    bf16*  wA   = (bf16*)alloc((size_t)ENUM * HDIM * IRD * 2);      // 67.1 MB
    bf16*  wB   = (bf16*)alloc((size_t)ENUM * HDIM * IRD * 2);      // 67.1 MB
    int*   e0a  = (int*)alloc(TTOK * 4);
    int*   e1a  = (int*)alloc(TTOK * 4);
    float* w0a  = (float*)alloc(TTOK * 4);
    float* w1a  = (float*)alloc(TTOK * 4);
    int*   disp = (int*)alloc(ENUM * CAP * 4);
    float* wrow = (float*)alloc(ENUM * CAP * 4);

    bf16* sgt = wA;                                  // [ISH][HDIM]
    bf16* sut = wA + (size_t)ISH * HDIM;
    bf16* sdt = wA + (size_t)2 * ISH * HDIM;         // [HDIM][ISH]

    hipMemsetAsync(d_out, 0, (size_t)out_size * 4, stream);

    router_kernel<<<TTOK, 256, 0, stream>>>(x, rtw, xb, e0a, e1a, w0a, w1a);
    dispatch_kernel<<<ENUM, 256, 0, stream>>>(e0a, e1a, w0a, w1a, disp, wrow);
    gather_kernel<<<ENUM * CAP, 256, 0, stream>>>(disp, xb, xg);

    // ---- shared expert first (writes out directly) ----
    tcvt_kernel<<<dim3(ISH / 32, HDIM / 32, 1), 256, 0, stream>>>(sg, sgt, HDIM, ISH);
    tcvt_kernel<<<dim3(ISH / 32, HDIM / 32, 1), 256, 0, stream>>>(su, sut, HDIM, ISH);
    tcvt_kernel<<<dim3(HDIM / 32, ISH / 32, 1), 256, 0, stream>>>(sd, sdt, ISH, HDIM);
    for (int c = 0; c < 2; ++c) {
        gemm_gu<<<dim3(ISH / 128, 4096 / 128, 1), 256, 0, stream>>>(
            xb + (size_t)c * 4096 * HDIM, sgt, sut, hbuf, ISH, HDIM, 0, 0, 0);
        gemm_down<0><<<dim3(HDIM / 128, 4096 / 128, 4), 256, 0, stream>>>(
            hbuf, sdt, out, nullptr, nullptr, ISH, c * 4096);
    }

    // ---- routed experts (atomic-scatter into out) ----
    tcvt_kernel<<<dim3(IRD / 32, HDIM / 32, ENUM), 256, 0, stream>>>(rg, wA, HDIM, IRD);
    tcvt_kernel<<<dim3(IRD / 32, HDIM / 32, ENUM), 256, 0, stream>>>(ru, wB, HDIM, IRD);
    gemm_gu<<<dim3(IRD / 128, CAP / 128, ENUM), 256, 0, stream>>>(
        xg, wA, wB, hbuf, IRD, HDIM,
        (long long)CAP * HDIM, (long long)HDIM * IRD, (long long)CAP * IRD);
    tcvt_kernel<<<dim3(HDIM / 32, IRD / 32, ENUM), 256, 0, stream>>>(rd, wA, IRD, HDIM);
    gemm_down<1><<<dim3(HDIM / 128, CAP / 128, ENUM * 2), 256, 0, stream>>>(
        hbuf, wA, out, disp, wrow, IRD, 0);
}